// Round 1
// baseline (1249.494 us; speedup 1.0000x reference)
//
#include <hip/hip_runtime.h>
#include <hip/hip_bf16.h>
#include <math.h>

#define NN 100000
#define EE 1600000
#define DD 128
#define HH 8
#define CC 16
#define EDD 16

// ---------------- CSR build ----------------

__global__ void k_hist(const int* __restrict__ ei, int* __restrict__ cnt) {
  int stride = gridDim.x * blockDim.x;
  for (int e = blockIdx.x * blockDim.x + threadIdx.x; e < EE; e += stride)
    atomicAdd(&cnt[ei[EE + e]], 1);
}

__global__ __launch_bounds__(1024) void k_scan(int* __restrict__ cur, int* __restrict__ off) {
  __shared__ int wpart[16];
  __shared__ int s_run;
  int t = threadIdx.x, lane = t & 63, w = t >> 6;
  if (t == 0) s_run = 0;
  __syncthreads();
  for (int base = 0; base < NN; base += 1024) {
    int i = base + t;
    int v = (i < NN) ? cur[i] : 0;
    int x = v;
#pragma unroll
    for (int d = 1; d < 64; d <<= 1) {
      int y = __shfl_up(x, d, 64);
      if (lane >= d) x += y;
    }
    if (lane == 63) wpart[w] = x;
    __syncthreads();
    if (w == 0) {
      int p = (lane < 16) ? wpart[lane] : 0;
#pragma unroll
      for (int d = 1; d < 16; d <<= 1) {
        int y = __shfl_up(p, d, 64);
        if (lane >= d) p += y;
      }
      if (lane < 16) wpart[lane] = p;
    }
    __syncthreads();
    int run = s_run;
    int excl = run + ((w > 0) ? wpart[w - 1] : 0) + (x - v);
    if (i < NN) { off[i] = excl; cur[i] = excl; }
    __syncthreads();
    if (t == 0) s_run = run + wpart[15];
    __syncthreads();
  }
  if (t == 0) off[NN] = s_run;
}

__global__ void k_scatter(const int* __restrict__ ei, int* __restrict__ cur,
                          int* __restrict__ perm) {
  int stride = gridDim.x * blockDim.x;
  for (int e = blockIdx.x * blockDim.x + threadIdx.x; e < EE; e += stride) {
    int d = ei[EE + e];
    int p = atomicAdd(&cur[d], 1);
    perm[p] = e;
  }
}

// ---------------- node transform: xh = x@lin_W, a_src, a_dst ----------------
// 256 thr, 64 rows/block; thread = 4 cols x 8 rows; W staged in 32-row k-tiles.

__global__ __launch_bounds__(256) void k_node(
    const float* __restrict__ x, const float* __restrict__ linW,
    const float* __restrict__ attS, const float* __restrict__ attD,
    float* __restrict__ xh, float* __restrict__ asrc, float* __restrict__ adst) {
  __shared__ float xs[64][129];
  __shared__ float wt[32][132];
  int t = threadIdx.x;
  int row0 = blockIdx.x * 64;
  for (int i = t; i < 64 * 32; i += 256) {
    int r = i >> 5, c4 = i & 31;
    float4 v = make_float4(0.f, 0.f, 0.f, 0.f);
    if (row0 + r < NN) v = ((const float4*)(x + (size_t)(row0 + r) * DD))[c4];
    xs[r][c4 * 4 + 0] = v.x; xs[r][c4 * 4 + 1] = v.y;
    xs[r][c4 * 4 + 2] = v.z; xs[r][c4 * 4 + 3] = v.w;
  }
  int cg = t & 31, rg = t >> 5;
  int j0 = cg * 4, rbase = rg * 8;
  float acc[8][4];
#pragma unroll
  for (int i = 0; i < 8; i++) { acc[i][0] = 0.f; acc[i][1] = 0.f; acc[i][2] = 0.f; acc[i][3] = 0.f; }
  for (int kt = 0; kt < DD; kt += 32) {
    __syncthreads();
    for (int i = t; i < 32 * 32; i += 256) {
      int kk = i >> 5, c4 = i & 31;
      float4 v = ((const float4*)(linW + (size_t)(kt + kk) * DD))[c4];
      wt[kk][c4 * 4 + 0] = v.x; wt[kk][c4 * 4 + 1] = v.y;
      wt[kk][c4 * 4 + 2] = v.z; wt[kk][c4 * 4 + 3] = v.w;
    }
    __syncthreads();
#pragma unroll
    for (int kk = 0; kk < 32; kk++) {
      float w0 = wt[kk][j0], w1 = wt[kk][j0 + 1], w2 = wt[kk][j0 + 2], w3 = wt[kk][j0 + 3];
#pragma unroll
      for (int i = 0; i < 8; i++) {
        float xv = xs[rbase + i][kt + kk];
        acc[i][0] += xv * w0; acc[i][1] += xv * w1;
        acc[i][2] += xv * w2; acc[i][3] += xv * w3;
      }
    }
  }
  float s0 = attS[j0], s1 = attS[j0 + 1], s2 = attS[j0 + 2], s3 = attS[j0 + 3];
  float d0 = attD[j0], d1 = attD[j0 + 1], d2 = attD[j0 + 2], d3 = attD[j0 + 3];
  int h = cg >> 2;
#pragma unroll
  for (int i = 0; i < 8; i++) {
    int row = row0 + rbase + i;
    float ps = acc[i][0] * s0 + acc[i][1] * s1 + acc[i][2] * s2 + acc[i][3] * s3;
    float pd = acc[i][0] * d0 + acc[i][1] * d1 + acc[i][2] * d2 + acc[i][3] * d3;
    ps += __shfl_xor(ps, 1, 64); ps += __shfl_xor(ps, 2, 64);
    pd += __shfl_xor(pd, 1, 64); pd += __shfl_xor(pd, 2, 64);
    if (row < NN) {
      ((float4*)(xh + (size_t)row * DD))[cg] =
          make_float4(acc[i][0], acc[i][1], acc[i][2], acc[i][3]);
      if ((cg & 3) == 0) { asrc[row * HH + h] = ps; adst[row * HH + h] = pd; }
    }
  }
}

// ---------------- edge aggregation + LN1 (one wave per dst node) ----------------
// lane l: column l -> head hA=l>>4, c=l&15 ; column 64+l -> head 4+hA.
// lin_edge_W columns held in registers; softmax uses m=0 (max cancels exactly).

__global__ __launch_bounds__(256) void k_agg(
    const int* __restrict__ ei, const float* __restrict__ eattr,
    const float* __restrict__ wle, const float* __restrict__ attE,
    const float* __restrict__ x, const float* __restrict__ xh,
    const float* __restrict__ asrc, const float* __restrict__ adst,
    const float* __restrict__ cbias, const float* __restrict__ ln1g,
    const float* __restrict__ ln1b, const int* __restrict__ off,
    const int* __restrict__ perm, float* __restrict__ hbuf) {
  int w = threadIdx.x >> 6, lane = threadIdx.x & 63;
  int n = blockIdx.x * 4 + w;
  if (n >= NN) return;
  float wl0[16], wl1[16];
#pragma unroll
  for (int k = 0; k < 16; k++) {
    wl0[k] = wle[k * 128 + lane];
    wl1[k] = wle[k * 128 + 64 + lane];
  }
  float ae0 = attE[lane], ae1 = attE[64 + lane];
  int hA = lane >> 4;
  float adA = adst[n * HH + hA], adB = adst[n * HH + 4 + hA];
  int start = off[n], end = off[n + 1];
  float accA = 0.f, accB = 0.f, sA = 0.f, sB = 0.f;
  int e_n = 0, src_n = 0;
  if (start < end) { e_n = perm[start]; src_n = ei[e_n]; }
  for (int ii = start; ii < end; ii++) {
    int e = e_n, src = src_n;
    if (ii + 1 < end) { e_n = perm[ii + 1]; src_n = ei[e_n]; }
    const float4* eap = (const float4*)(eattr + (size_t)e * EDD);
    float4 ea0 = eap[0], ea1 = eap[1], ea2 = eap[2], ea3 = eap[3];
    float ea[16] = {ea0.x, ea0.y, ea0.z, ea0.w, ea1.x, ea1.y, ea1.z, ea1.w,
                    ea2.x, ea2.y, ea2.z, ea2.w, ea3.x, ea3.y, ea3.z, ea3.w};
    float ev0 = 0.f, ev1 = 0.f;
#pragma unroll
    for (int k = 0; k < 16; k++) { ev0 += ea[k] * wl0[k]; ev1 += ea[k] * wl1[k]; }
    float p0 = ev0 * ae0, p1 = ev1 * ae1;
#pragma unroll
    for (int m = 1; m < 16; m <<= 1) { p0 += __shfl_xor(p0, m, 64); p1 += __shfl_xor(p1, m, 64); }
    float al0 = asrc[src * HH + hA] + adA + p0;
    float al1 = asrc[src * HH + 4 + hA] + adB + p1;
    al0 = (al0 >= 0.f) ? al0 : 0.2f * al0;
    al1 = (al1 >= 0.f) ? al1 : 0.2f * al1;
    float ex0 = __expf(al0), ex1 = __expf(al1);
    sA += ex0; sB += ex1;
    float xh0 = xh[(size_t)src * DD + lane];
    float xh1 = xh[(size_t)src * DD + 64 + lane];
    accA += ex0 * xh0 * ev0;
    accB += ex1 * xh1 * ev1;
  }
  float o0 = accA / (sA + 1e-16f) + cbias[lane];
  float o1 = accB / (sB + 1e-16f) + cbias[64 + lane];
  float v0 = x[(size_t)n * DD + lane] + o0;
  float v1 = x[(size_t)n * DD + 64 + lane] + o1;
  float sum = v0 + v1;
#pragma unroll
  for (int m = 1; m < 64; m <<= 1) sum += __shfl_xor(sum, m, 64);
  float mu = sum * (1.f / 128.f);
  float q0 = v0 - mu, q1 = v1 - mu;
  float vs = q0 * q0 + q1 * q1;
#pragma unroll
  for (int m = 1; m < 64; m <<= 1) vs += __shfl_xor(vs, m, 64);
  float rs = rsqrtf(vs * (1.f / 128.f) + 1e-5f);
  hbuf[(size_t)n * DD + lane]      = q0 * rs * ln1g[lane]      + ln1b[lane];
  hbuf[(size_t)n * DD + 64 + lane] = q1 * rs * ln1g[64 + lane] + ln1b[64 + lane];
}

// ---------------- MLP GEMM 1: G = gelu(h@W1+b1) ----------------

__global__ __launch_bounds__(256) void k_mlp1(
    const float* __restrict__ hb, const float* __restrict__ W1,
    const float* __restrict__ mb1, float* __restrict__ G) {
  __shared__ float xs[64][129];
  __shared__ float wt[32][132];
  int t = threadIdx.x;
  int row0 = blockIdx.x * 64;
  for (int i = t; i < 64 * 32; i += 256) {
    int r = i >> 5, c4 = i & 31;
    float4 v = make_float4(0.f, 0.f, 0.f, 0.f);
    if (row0 + r < NN) v = ((const float4*)(hb + (size_t)(row0 + r) * DD))[c4];
    xs[r][c4 * 4 + 0] = v.x; xs[r][c4 * 4 + 1] = v.y;
    xs[r][c4 * 4 + 2] = v.z; xs[r][c4 * 4 + 3] = v.w;
  }
  int cg = t & 31, rg = t >> 5;
  int j0 = cg * 4, rbase = rg * 8;
  float acc[8][4];
#pragma unroll
  for (int i = 0; i < 8; i++) { acc[i][0] = 0.f; acc[i][1] = 0.f; acc[i][2] = 0.f; acc[i][3] = 0.f; }
  for (int kt = 0; kt < DD; kt += 32) {
    __syncthreads();
    for (int i = t; i < 32 * 32; i += 256) {
      int kk = i >> 5, c4 = i & 31;
      float4 v = ((const float4*)(W1 + (size_t)(kt + kk) * DD))[c4];
      wt[kk][c4 * 4 + 0] = v.x; wt[kk][c4 * 4 + 1] = v.y;
      wt[kk][c4 * 4 + 2] = v.z; wt[kk][c4 * 4 + 3] = v.w;
    }
    __syncthreads();
#pragma unroll
    for (int kk = 0; kk < 32; kk++) {
      float w0 = wt[kk][j0], w1 = wt[kk][j0 + 1], w2 = wt[kk][j0 + 2], w3 = wt[kk][j0 + 3];
#pragma unroll
      for (int i = 0; i < 8; i++) {
        float xv = xs[rbase + i][kt + kk];
        acc[i][0] += xv * w0; acc[i][1] += xv * w1;
        acc[i][2] += xv * w2; acc[i][3] += xv * w3;
      }
    }
  }
  float b0 = mb1[j0], b1 = mb1[j0 + 1], b2 = mb1[j0 + 2], b3 = mb1[j0 + 3];
#pragma unroll
  for (int i = 0; i < 8; i++) {
    int row = row0 + rbase + i;
    if (row < NN) {
      float z0 = acc[i][0] + b0, z1 = acc[i][1] + b1, z2 = acc[i][2] + b2, z3 = acc[i][3] + b3;
      const float r2 = 0.70710678118654752f;
      float g0 = 0.5f * z0 * (1.f + erff(z0 * r2));
      float g1 = 0.5f * z1 * (1.f + erff(z1 * r2));
      float g2 = 0.5f * z2 * (1.f + erff(z2 * r2));
      float g3 = 0.5f * z3 * (1.f + erff(z3 * r2));
      ((float4*)(G + (size_t)row * DD))[cg] = make_float4(g0, g1, g2, g3);
    }
  }
}

// ---------------- MLP GEMM 2 + residual + LN2 -> out ----------------

__global__ __launch_bounds__(256) void k_mlp2(
    const float* __restrict__ G, const float* __restrict__ W2,
    const float* __restrict__ mb2, const float* __restrict__ hb,
    const float* __restrict__ ln2g, const float* __restrict__ ln2b,
    float* __restrict__ out) {
  __shared__ float xs[64][129];
  __shared__ float wt[32][132];
  int t = threadIdx.x;
  int row0 = blockIdx.x * 64;
  for (int i = t; i < 64 * 32; i += 256) {
    int r = i >> 5, c4 = i & 31;
    float4 v = make_float4(0.f, 0.f, 0.f, 0.f);
    if (row0 + r < NN) v = ((const float4*)(G + (size_t)(row0 + r) * DD))[c4];
    xs[r][c4 * 4 + 0] = v.x; xs[r][c4 * 4 + 1] = v.y;
    xs[r][c4 * 4 + 2] = v.z; xs[r][c4 * 4 + 3] = v.w;
  }
  int cg = t & 31, rg = t >> 5;
  int j0 = cg * 4, rbase = rg * 8;
  float acc[8][4];
#pragma unroll
  for (int i = 0; i < 8; i++) { acc[i][0] = 0.f; acc[i][1] = 0.f; acc[i][2] = 0.f; acc[i][3] = 0.f; }
  for (int kt = 0; kt < DD; kt += 32) {
    __syncthreads();
    for (int i = t; i < 32 * 32; i += 256) {
      int kk = i >> 5, c4 = i & 31;
      float4 v = ((const float4*)(W2 + (size_t)(kt + kk) * DD))[c4];
      wt[kk][c4 * 4 + 0] = v.x; wt[kk][c4 * 4 + 1] = v.y;
      wt[kk][c4 * 4 + 2] = v.z; wt[kk][c4 * 4 + 3] = v.w;
    }
    __syncthreads();
#pragma unroll
    for (int kk = 0; kk < 32; kk++) {
      float w0 = wt[kk][j0], w1 = wt[kk][j0 + 1], w2 = wt[kk][j0 + 2], w3 = wt[kk][j0 + 3];
#pragma unroll
      for (int i = 0; i < 8; i++) {
        float xv = xs[rbase + i][kt + kk];
        acc[i][0] += xv * w0; acc[i][1] += xv * w1;
        acc[i][2] += xv * w2; acc[i][3] += xv * w3;
      }
    }
  }
  float b0 = mb2[j0], b1 = mb2[j0 + 1], b2 = mb2[j0 + 2], b3 = mb2[j0 + 3];
  float g0 = ln2g[j0], g1 = ln2g[j0 + 1], g2 = ln2g[j0 + 2], g3 = ln2g[j0 + 3];
  float c0 = ln2b[j0], c1 = ln2b[j0 + 1], c2 = ln2b[j0 + 2], c3 = ln2b[j0 + 3];
#pragma unroll
  for (int i = 0; i < 8; i++) {
    int row = row0 + rbase + i;
    float4 hv = make_float4(0.f, 0.f, 0.f, 0.f);
    if (row < NN) hv = ((const float4*)(hb + (size_t)row * DD))[cg];
    float v0 = hv.x + acc[i][0] + b0;
    float v1 = hv.y + acc[i][1] + b1;
    float v2 = hv.z + acc[i][2] + b2;
    float v3 = hv.w + acc[i][3] + b3;
    float ps = v0 + v1 + v2 + v3;
#pragma unroll
    for (int m = 1; m < 32; m <<= 1) ps += __shfl_xor(ps, m, 64);
    float mu = ps * (1.f / 128.f);
    float q0 = v0 - mu, q1 = v1 - mu, q2 = v2 - mu, q3 = v3 - mu;
    float qs = q0 * q0 + q1 * q1 + q2 * q2 + q3 * q3;
#pragma unroll
    for (int m = 1; m < 32; m <<= 1) qs += __shfl_xor(qs, m, 64);
    float rs = rsqrtf(qs * (1.f / 128.f) + 1e-5f);
    if (row < NN) {
      ((float4*)(out + (size_t)row * DD))[cg] =
          make_float4(q0 * rs * g0 + c0, q1 * rs * g1 + c1,
                      q2 * rs * g2 + c2, q3 * rs * g3 + c3);
    }
  }
}

// ---------------- launcher ----------------

extern "C" void kernel_launch(void* const* d_in, const int* in_sizes, int n_in,
                              void* d_out, int out_size, void* d_ws, size_t ws_size,
                              hipStream_t stream) {
  const float* x     = (const float*)d_in[0];
  const int*   ei    = (const int*)d_in[1];
  const float* eattr = (const float*)d_in[2];
  const float* linW  = (const float*)d_in[3];
  const float* attS  = (const float*)d_in[4];
  const float* attD  = (const float*)d_in[5];
  const float* wle   = (const float*)d_in[6];
  const float* attE  = (const float*)d_in[7];
  const float* cbias = (const float*)d_in[8];
  const float* ln1g  = (const float*)d_in[9];
  const float* ln1b  = (const float*)d_in[10];
  const float* W1    = (const float*)d_in[11];
  const float* mb1   = (const float*)d_in[12];
  const float* W2    = (const float*)d_in[13];
  const float* mb2   = (const float*)d_in[14];
  const float* ln2g  = (const float*)d_in[15];
  const float* ln2b  = (const float*)d_in[16];

  char* ws = (char*)d_ws;
  float* xh   = (float*)(ws + 0);          // N*128 f32, later reused as G
  float* hbuf = (float*)(ws + 51200000);   // N*128 f32
  float* asrc = (float*)(ws + 102400000);  // N*8
  float* adst = (float*)(ws + 105600000);  // N*8
  int*   off  = (int*)  (ws + 108800000);  // N+1
  int*   cur  = (int*)  (ws + 109200128);  // N
  int*   perm = (int*)  (ws + 109600256);  // E
  float* outp = (float*)d_out;

  hipMemsetAsync(cur, 0, NN * sizeof(int), stream);
  k_hist<<<4096, 256, 0, stream>>>(ei, cur);
  k_scan<<<1, 1024, 0, stream>>>(cur, off);
  k_scatter<<<4096, 256, 0, stream>>>(ei, cur, perm);
  k_node<<<(NN + 63) / 64, 256, 0, stream>>>(x, linW, attS, attD, xh, asrc, adst);
  k_agg<<<(NN + 3) / 4, 256, 0, stream>>>(ei, eattr, wle, attE, x, xh, asrc, adst,
                                          cbias, ln1g, ln1b, off, perm, hbuf);
  k_mlp1<<<(NN + 63) / 64, 256, 0, stream>>>(hbuf, W1, mb1, xh);
  k_mlp2<<<(NN + 63) / 64, 256, 0, stream>>>(xh, W2, mb2, hbuf, ln2g, ln2b, outp);
}

// Round 4
// 1019.332 us; speedup vs baseline: 1.2258x; 1.2258x over previous
//
#include <hip/hip_runtime.h>
#include <hip/hip_bf16.h>
#include <math.h>

#define NN 100000
#define EE 1600000
#define DD 128
#define HH 8
#define CC 16
#define EDD 16
#define NBLK 98  // ceil(NN/1024)

typedef unsigned short u16;
typedef unsigned int u32;
typedef __attribute__((ext_vector_type(8))) short short8;
typedef __attribute__((ext_vector_type(4))) float f32x4;

__device__ __forceinline__ u16 f2bf(float f) {
  u32 u = __float_as_uint(f);
  u32 r = u + 0x7fff + ((u >> 16) & 1);
  return (u16)(r >> 16);
}

// ---------------- CSR build ----------------

__global__ void k_hist(const int* __restrict__ ei, int* __restrict__ cnt) {
  int stride = gridDim.x * blockDim.x;
  for (int e = blockIdx.x * blockDim.x + threadIdx.x; e < EE; e += stride)
    atomicAdd(&cnt[ei[EE + e]], 1);
}

__global__ __launch_bounds__(1024) void k_scan_a(const int* __restrict__ cnt,
                                                 int* __restrict__ loc,
                                                 int* __restrict__ bsum) {
  __shared__ int wpart[16];
  int t = threadIdx.x, lane = t & 63, w = t >> 6;
  int i = blockIdx.x * 1024 + t;
  int v = (i < NN) ? cnt[i] : 0;
  int x = v;
#pragma unroll
  for (int d = 1; d < 64; d <<= 1) {
    int y = __shfl_up(x, d, 64);
    if (lane >= d) x += y;
  }
  if (lane == 63) wpart[w] = x;
  __syncthreads();
  if (w == 0) {
    int p = (lane < 16) ? wpart[lane] : 0;
#pragma unroll
    for (int d = 1; d < 16; d <<= 1) {
      int y = __shfl_up(p, d, 64);
      if (lane >= d) p += y;
    }
    if (lane < 16) wpart[lane] = p;
  }
  __syncthreads();
  int excl = ((w > 0) ? wpart[w - 1] : 0) + (x - v);
  if (i < NN) loc[i] = excl;
  if (t == 0) bsum[blockIdx.x] = wpart[15];
}

__global__ void k_scan_b(int* __restrict__ bsum, int* __restrict__ off) {
  if (blockIdx.x == 0 && threadIdx.x == 0) {
    int run = 0;
    for (int b = 0; b < NBLK; b++) { int s = bsum[b]; bsum[b] = run; run += s; }
    off[NN] = run;
  }
}

__global__ __launch_bounds__(1024) void k_scan_c(const int* __restrict__ loc,
                                                 const int* __restrict__ bsum,
                                                 int* __restrict__ off,
                                                 int* __restrict__ cur) {
  int i = blockIdx.x * 1024 + threadIdx.x;
  if (i < NN) {
    int v = loc[i] + bsum[i >> 10];
    off[i] = v;
    cur[i] = v;
  }
}

__global__ void k_scatter(const int* __restrict__ ei, int* __restrict__ cur,
                          int* __restrict__ perm) {
  int stride = gridDim.x * blockDim.x;
  for (int e = blockIdx.x * blockDim.x + threadIdx.x; e < EE; e += stride) {
    int d = ei[EE + e];
    int p = atomicAdd(&cur[d], 1);
    perm[p] = e;
  }
}

// ---------------- gather eattr/src into CSR order ----------------

__global__ void k_gather(const int* __restrict__ perm, const int* __restrict__ ei,
                         const float* __restrict__ eattr, float* __restrict__ eattrP,
                         int* __restrict__ srcP) {
  int stride = gridDim.x * blockDim.x;
  for (int c = blockIdx.x * blockDim.x + threadIdx.x; c < EE * 4; c += stride) {
    int ii = c >> 2, q = c & 3;
    int e = perm[ii];
    ((float4*)eattrP)[ii * 4 + q] = ((const float4*)eattr)[e * 4 + q];
    if (q == 0) srcP[ii] = ei[e];
  }
}

// ---------------- prep: bf16-transposed weights + WA ----------------
// Btg[m][n][k] = bf16(W_m[k][n]);  WAg[k][h] = sum_c Wle[k][16h+c]*attE[16h+c]

__global__ void k_prep(const float* __restrict__ linW, const float* __restrict__ W1,
                       const float* __restrict__ W2, const float* __restrict__ wle,
                       const float* __restrict__ attE, u16* __restrict__ Btg,
                       float* __restrict__ WAg) {
  int tid = blockIdx.x * 256 + threadIdx.x;
  if (tid < 6144) {
    int m = tid >> 11;
    int cid = tid & 2047;
    const float* W = (m == 0) ? linW : (m == 1) ? W1 : W2;
    int n = cid >> 4, kc = cid & 15;
    union { u16 us[8]; uint4 q4; } P;
#pragma unroll
    for (int j = 0; j < 8; j++) P.us[j] = f2bf(W[(kc * 8 + j) * 128 + n]);
    ((uint4*)(Btg + (size_t)m * 16384))[cid] = P.q4;
  } else if (tid < 6272) {
    int i = tid - 6144;
    int k = i >> 3, h = i & 7;
    float s = 0.f;
#pragma unroll
    for (int c = 0; c < 16; c++) s += wle[k * 128 + h * 16 + c] * attE[h * 16 + c];
    WAg[k * 8 + h] = s;
  }
}

// ---------------- bf16 MFMA GEMM: [N x 128] @ [128 x 128] ----------------
// EPI: 0 = plain store, 1 = bias+gelu, 2 = bias+residual+LN2

template <int EPI>
__global__ __launch_bounds__(256) void k_gemm(
    const float* __restrict__ A, const u16* __restrict__ Bt,
    const float* __restrict__ bias, const float* __restrict__ resid,
    const float* __restrict__ lng, const float* __restrict__ lnb,
    float* __restrict__ Cout) {
  __shared__ u16 As[64 * 136];
  __shared__ u16 Bs[128 * 136];
  int t = threadIdx.x;
  int row0 = blockIdx.x * 64;
  // stage B (bf16 [n][k] rows, padded stride 136)
#pragma unroll
  for (int i = 0; i < 8; i++) {
    int cid = t + 256 * i;
    int n = cid >> 4, kc = cid & 15;
    uint4 v = ((const uint4*)Bt)[cid];
    *((uint4*)(&Bs[n * 136 + kc * 8])) = v;
  }
  // stage A (f32 -> bf16)
  {
    int r = t >> 2, q = t & 3;
    const float* Ar = A + (size_t)(row0 + r) * 128 + q * 32;
    bool ok = (row0 + r) < NN;
#pragma unroll
    for (int j = 0; j < 4; j++) {
      float4 u = ok ? ((const float4*)Ar)[2 * j] : make_float4(0.f, 0.f, 0.f, 0.f);
      float4 v = ok ? ((const float4*)Ar)[2 * j + 1] : make_float4(0.f, 0.f, 0.f, 0.f);
      union { u16 us[8]; uint4 q4; } P;
      P.us[0] = f2bf(u.x); P.us[1] = f2bf(u.y); P.us[2] = f2bf(u.z); P.us[3] = f2bf(u.w);
      P.us[4] = f2bf(v.x); P.us[5] = f2bf(v.y); P.us[6] = f2bf(v.z); P.us[7] = f2bf(v.w);
      *((uint4*)(&As[r * 136 + (q * 4 + j) * 8])) = P.q4;
    }
  }
  __syncthreads();
  int w = t >> 6, lane = t & 63, lo = lane & 15, hi = lane >> 4;
  f32x4 acc[8];
  f32x4 zero = {0.f, 0.f, 0.f, 0.f};
#pragma unroll
  for (int i = 0; i < 8; i++) acc[i] = zero;
  const u16* ApL = &As[(w * 16 + lo) * 136];
  const u16* BpL = &Bs[lo * 136];
#pragma unroll
  for (int ks = 0; ks < 4; ks++) {
    short8 af = *((const short8*)(ApL + ks * 32 + hi * 8));
#pragma unroll
    for (int tt = 0; tt < 8; tt++) {
      short8 bf = *((const short8*)(BpL + tt * 16 * 136 + ks * 32 + hi * 8));
      acc[tt] = __builtin_amdgcn_mfma_f32_16x16x32_bf16(af, bf, acc[tt], 0, 0, 0);
    }
  }
  // epilogue
  if (EPI == 0) {
#pragma unroll
    for (int j = 0; j < 4; j++) {
      int row = row0 + w * 16 + hi * 4 + j;
      if (row < NN) {
#pragma unroll
        for (int tt = 0; tt < 8; tt++)
          Cout[(size_t)row * 128 + tt * 16 + lo] = acc[tt][j];
      }
    }
  } else if (EPI == 1) {
#pragma unroll
    for (int j = 0; j < 4; j++) {
      int row = row0 + w * 16 + hi * 4 + j;
      if (row < NN) {
#pragma unroll
        for (int tt = 0; tt < 8; tt++) {
          int col = tt * 16 + lo;
          float z = acc[tt][j] + bias[col];
          float g = 0.5f * z * (1.f + erff(z * 0.70710678118654752f));
          Cout[(size_t)row * 128 + col] = g;
        }
      }
    }
  } else {
#pragma unroll
    for (int j = 0; j < 4; j++) {
      int row = row0 + w * 16 + hi * 4 + j;
      bool rok = row < NN;
      float v[8];
      float sum = 0.f;
#pragma unroll
      for (int tt = 0; tt < 8; tt++) {
        int col = tt * 16 + lo;
        float hv = rok ? resid[(size_t)row * 128 + col] : 0.f;
        v[tt] = hv + acc[tt][j] + bias[col];
        sum += v[tt];
      }
      sum += __shfl_xor(sum, 1, 64); sum += __shfl_xor(sum, 2, 64);
      sum += __shfl_xor(sum, 4, 64); sum += __shfl_xor(sum, 8, 64);
      float mu = sum * (1.f / 128.f);
      float var = 0.f;
#pragma unroll
      for (int tt = 0; tt < 8; tt++) { v[tt] -= mu; var += v[tt] * v[tt]; }
      var += __shfl_xor(var, 1, 64); var += __shfl_xor(var, 2, 64);
      var += __shfl_xor(var, 4, 64); var += __shfl_xor(var, 8, 64);
      float rs = rsqrtf(var * (1.f / 128.f) + 1e-5f);
      if (rok) {
#pragma unroll
        for (int tt = 0; tt < 8; tt++) {
          int col = tt * 16 + lo;
          Cout[(size_t)row * 128 + col] = v[tt] * rs * lng[col] + lnb[col];
        }
      }
    }
  }
}

// ---------------- attention scalars: asrc/adst from xh ----------------

__global__ __launch_bounds__(256) void k_att(const float* __restrict__ xh,
                                             const float* __restrict__ attS,
                                             const float* __restrict__ attD,
                                             float* __restrict__ asrc,
                                             float* __restrict__ adst) {
  int w = threadIdx.x >> 6, lane = threadIdx.x & 63;
  int n = blockIdx.x * 4 + w;
  if (n >= NN) return;
  float v0 = xh[(size_t)n * 128 + lane];
  float v1 = xh[(size_t)n * 128 + 64 + lane];
  float s0 = v0 * attS[lane], s1 = v1 * attS[64 + lane];
  float d0 = v0 * attD[lane], d1 = v1 * attD[64 + lane];
#pragma unroll
  for (int m = 1; m < 16; m <<= 1) {
    s0 += __shfl_xor(s0, m, 64); s1 += __shfl_xor(s1, m, 64);
    d0 += __shfl_xor(d0, m, 64); d1 += __shfl_xor(d1, m, 64);
  }
  if ((lane & 15) == 0) {
    int h = lane >> 4;
    asrc[n * HH + h] = s0; asrc[n * HH + 4 + h] = s1;
    adst[n * HH + h] = d0; adst[n * HH + 4 + h] = d1;
  }
}

// ---------------- edge aggregation + LN1 (one wave per dst node) ----------------
// lane covers cols (2l, 2l+1); head h = l>>3. No cross-lane ops in edge loop.

template <bool GATHER>
__global__ __launch_bounds__(256, 4) void k_agg(
    const int* __restrict__ ei, const float* __restrict__ eattr,
    const float* __restrict__ eattrP, const int* __restrict__ srcP,
    const int* __restrict__ perm, const float* __restrict__ wle,
    const float* __restrict__ wag, const float* __restrict__ x,
    const float* __restrict__ xh, const float* __restrict__ asrc,
    const float* __restrict__ adst, const float* __restrict__ cbias,
    const float* __restrict__ ln1g, const float* __restrict__ ln1b,
    const int* __restrict__ off, float* __restrict__ hbuf) {
  int w = threadIdx.x >> 6, lane = threadIdx.x & 63;
  int n = blockIdx.x * 4 + w;
  if (n >= NN) return;
  int h = lane >> 3;
  float wlA[16], wlB[16], wa[16];
#pragma unroll
  for (int k = 0; k < 16; k++) {
    float2 tv = *(const float2*)(wle + k * 128 + 2 * lane);
    wlA[k] = tv.x; wlB[k] = tv.y;
    wa[k] = wag[k * 8 + h];
  }
  float ad = adst[n * HH + h];
  int st = off[n], cnt = off[n + 1] - st;
  float accA = 0.f, accB = 0.f, ssum = 0.f;

  const float* erows = GATHER ? eattrP : eattr;

  // position -> src index / eattr row id (guarded; defaults hit valid addr 0)
#define SRCQ(q) ((q) < cnt ? (GATHER ? srcP[st + (q)] : ei[perm[st + (q)]]) : 0)
#define ROWQ(q) ((q) < cnt ? (GATHER ? (st + (q)) : perm[st + (q)]) : 0)

  int s0 = SRCQ(0), s1 = SRCQ(1);
  int r0 = ROWQ(0);
  const float4* p0 = (const float4*)(erows + (size_t)r0 * 16);
  float4 a0 = p0[0], a1 = p0[1], a2 = p0[2], a3 = p0[3];
  float2 xf0 = *(const float2*)(xh + (size_t)s0 * 128 + 2 * lane);
  float as0 = asrc[s0 * HH + h];
  float2 xf1 = *(const float2*)(xh + (size_t)s1 * 128 + 2 * lane);
  float as1 = asrc[s1 * HH + h];

  for (int q = 0; q < cnt; ++q) {
    // prefetch eattr for q+1
    int r1 = ROWQ(q + 1);
    const float4* pn = (const float4*)(erows + (size_t)r1 * 16);
    float4 b0 = pn[0], b1 = pn[1], b2 = pn[2], b3 = pn[3];
    // prefetch src/xh/asrc for q+2
    int s2 = SRCQ(q + 2);
    float2 xf2 = *(const float2*)(xh + (size_t)s2 * 128 + 2 * lane);
    float as2 = asrc[s2 * HH + h];
    // compute edge q
    float ea[16] = {a0.x, a0.y, a0.z, a0.w, a1.x, a1.y, a1.z, a1.w,
                    a2.x, a2.y, a2.z, a2.w, a3.x, a3.y, a3.z, a3.w};
    float evA = 0.f, evB = 0.f, pe = 0.f;
#pragma unroll
    for (int k = 0; k < 16; k++) {
      evA += ea[k] * wlA[k];
      evB += ea[k] * wlB[k];
      pe += ea[k] * wa[k];
    }
    float al = as0 + ad + pe;
    al = (al >= 0.f) ? al : 0.2f * al;
    float ex = __expf(al);
    ssum += ex;
    accA += ex * xf0.x * evA;
    accB += ex * xf0.y * evB;
    // rotate
    a0 = b0; a1 = b1; a2 = b2; a3 = b3;
    xf0 = xf1; as0 = as1;
    xf1 = xf2; as1 = as2;
  }
#undef SRCQ
#undef ROWQ

  float inv = 1.f / (ssum + 1e-16f);
  float2 cb = *(const float2*)(cbias + 2 * lane);
  float2 xv = *(const float2*)(x + (size_t)n * 128 + 2 * lane);
  float v0 = xv.x + accA * inv + cb.x;
  float v1 = xv.y + accB * inv + cb.y;
  float sum = v0 + v1;
#pragma unroll
  for (int m = 1; m < 64; m <<= 1) sum += __shfl_xor(sum, m, 64);
  float mu = sum * (1.f / 128.f);
  float q0 = v0 - mu, q1 = v1 - mu;
  float vs = q0 * q0 + q1 * q1;
#pragma unroll
  for (int m = 1; m < 64; m <<= 1) vs += __shfl_xor(vs, m, 64);
  float rs = rsqrtf(vs * (1.f / 128.f) + 1e-5f);
  float2 g = *(const float2*)(ln1g + 2 * lane);
  float2 b = *(const float2*)(ln1b + 2 * lane);
  float2 o;
  o.x = q0 * rs * g.x + b.x;
  o.y = q1 * rs * g.y + b.y;
  *(float2*)(hbuf + (size_t)n * 128 + 2 * lane) = o;
}

// ---------------- launcher ----------------

#define WS_XH 0ull
#define WS_HBUF 51200000ull
#define WS_ASRC 102400000ull
#define WS_ADST 105600000ull
#define WS_OFF 108800000ull
#define WS_CUR 109200128ull
#define WS_PERM 109600128ull
#define WS_WAG 116000128ull
#define WS_BTG 116000640ull
#define WS_SRCP 116098944ull
#define WS_EATTRP 122498944ull
#define WS_NEED_GATHER 224898944ull

extern "C" void kernel_launch(void* const* d_in, const int* in_sizes, int n_in,
                              void* d_out, int out_size, void* d_ws, size_t ws_size,
                              hipStream_t stream) {
  const float* x     = (const float*)d_in[0];
  const int*   ei    = (const int*)d_in[1];
  const float* eattr = (const float*)d_in[2];
  const float* linW  = (const float*)d_in[3];
  const float* attS  = (const float*)d_in[4];
  const float* attD  = (const float*)d_in[5];
  const float* wle   = (const float*)d_in[6];
  const float* attE  = (const float*)d_in[7];
  const float* cbias = (const float*)d_in[8];
  const float* ln1g  = (const float*)d_in[9];
  const float* ln1b  = (const float*)d_in[10];
  const float* W1    = (const float*)d_in[11];
  const float* mb1   = (const float*)d_in[12];
  const float* W2    = (const float*)d_in[13];
  const float* mb2   = (const float*)d_in[14];
  const float* ln2g  = (const float*)d_in[15];
  const float* ln2b  = (const float*)d_in[16];

  char* ws = (char*)d_ws;
  float* xh     = (float*)(ws + WS_XH);
  float* hbuf   = (float*)(ws + WS_HBUF);
  float* asrc   = (float*)(ws + WS_ASRC);
  float* adst   = (float*)(ws + WS_ADST);
  int*   off    = (int*)(ws + WS_OFF);
  int*   cur    = (int*)(ws + WS_CUR);
  int*   perm   = (int*)(ws + WS_PERM);
  float* WAg    = (float*)(ws + WS_WAG);
  u16*   Btg    = (u16*)(ws + WS_BTG);
  int*   srcP   = (int*)(ws + WS_SRCP);
  float* eattrP = (float*)(ws + WS_EATTRP);
  int*   loc    = (int*)(ws + WS_XH);    // scan scratch (xh region, free pre-k_node)
  int*   bsum   = (int*)(ws + WS_ADST);  // 98 ints (adst region, free pre-k_att)
  float* outp   = (float*)d_out;

  bool gather = ws_size >= WS_NEED_GATHER;

  hipMemsetAsync(cur, 0, NN * sizeof(int), stream);
  k_hist<<<4096, 256, 0, stream>>>(ei, cur);
  k_scan_a<<<NBLK, 1024, 0, stream>>>(cur, loc, bsum);
  k_scan_b<<<1, 64, 0, stream>>>(bsum, off);
  k_scan_c<<<NBLK, 1024, 0, stream>>>(loc, bsum, off, cur);
  k_scatter<<<4096, 256, 0, stream>>>(ei, cur, perm);
  k_prep<<<25, 256, 0, stream>>>(linW, W1, W2, wle, attE, Btg, WAg);
  if (gather)
    k_gather<<<4096, 256, 0, stream>>>(perm, ei, eattr, eattrP, srcP);
  // xh = x @ lin_W  (bf16 MFMA)
  k_gemm<0><<<(NN + 63) / 64, 256, 0, stream>>>(x, Btg, x, x, x, x, xh);
  k_att<<<(NN + 3) / 4, 256, 0, stream>>>(xh, attS, attD, asrc, adst);
  if (gather)
    k_agg<true><<<(NN + 3) / 4, 256, 0, stream>>>(
        ei, eattr, eattrP, srcP, perm, wle, WAg, x, xh, asrc, adst, cbias,
        ln1g, ln1b, off, hbuf);
  else
    k_agg<false><<<(NN + 3) / 4, 256, 0, stream>>>(
        ei, eattr, eattrP, srcP, perm, wle, WAg, x, xh, asrc, adst, cbias,
        ln1g, ln1b, off, hbuf);
  // G = gelu(h @ W1 + b1)  -> reuse xh buffer
  k_gemm<1><<<(NN + 63) / 64, 256, 0, stream>>>(hbuf, Btg + 16384, mb1, hbuf,
                                                ln2g, ln2b, xh);
  // out = LN2(h + G @ W2 + b2)
  k_gemm<2><<<(NN + 63) / 64, 256, 0, stream>>>(xh, Btg + 32768, mb2, hbuf,
                                                ln2g, ln2b, outp);
}